// Round 8
// baseline (407.366 us; speedup 1.0000x reference)
//
#include <hip/hip_runtime.h>
#include <hip/hip_bf16.h>
#include <hip/hip_fp8.h>
#include <math.h>

#define N 8192
#define D 512
#define BM 128
#define BKB 128                         // K-bytes per chunk (fp8), 4 chunks
#define NSTRIP 64                       // N / BM
#define S_BLOCKS (NSTRIP * NSTRIP)      // 4096 blocks, 1 tile each
#define TRI (NSTRIP * (NSTRIP + 1) / 2) // 2080
#define G_BLOCKS (2 * TRI)              // 4160 blocks, 1 tile each

typedef float f32x4 __attribute__((ext_vector_type(4)));
typedef int i32x4 __attribute__((ext_vector_type(4)));
typedef int i32x8 __attribute__((ext_vector_type(8)));

__device__ inline void gload_lds16(const void* g, void* l) {
  __builtin_amdgcn_global_load_lds(
      (const __attribute__((address_space(1))) void*)g,
      (__attribute__((address_space(3))) void*)l, 16, 0, 0);
}

// ---------------- normalize to fp8 e4m3 + exact fp32 diagonal ----------------
__global__ __launch_bounds__(256) void norm_kernel(
    const float* __restrict__ z1, const float* __restrict__ z2,
    unsigned char* __restrict__ q1, unsigned char* __restrict__ q2,
    float* __restrict__ diag) {
  int row = blockIdx.x;
  int t = threadIdx.x;
  const float* a = z1 + (size_t)row * D;
  const float* b = z2 + (size_t)row * D;
  float va[2], vb[2];
  float ss1 = 0.f, ss2 = 0.f, dd = 0.f;
#pragma unroll
  for (int i = 0; i < 2; i++) {
    float x = a[t + 256 * i];
    float y = b[t + 256 * i];
    va[i] = x; vb[i] = y;
    ss1 += x * x; ss2 += y * y; dd += x * y;
  }
#pragma unroll
  for (int off = 1; off < 64; off <<= 1) {
    ss1 += __shfl_xor(ss1, off);
    ss2 += __shfl_xor(ss2, off);
    dd  += __shfl_xor(dd,  off);
  }
  __shared__ float red[3][4];
  int wv = t >> 6;
  if ((t & 63) == 0) { red[0][wv] = ss1; red[1][wv] = ss2; red[2][wv] = dd; }
  __syncthreads();
  ss1 = red[0][0] + red[0][1] + red[0][2] + red[0][3];
  ss2 = red[1][0] + red[1][1] + red[1][2] + red[1][3];
  dd  = red[2][0] + red[2][1] + red[2][2] + red[2][3];
  float i1 = 1.0f / fmaxf(sqrtf(ss1), 1e-12f);
  float i2 = 1.0f / fmaxf(sqrtf(ss2), 1e-12f);
#pragma unroll
  for (int i = 0; i < 2; i++) {
    __hip_fp8_e4m3 c1((float)(va[i] * i1)); // OCP e4m3fn
    __hip_fp8_e4m3 c2((float)(vb[i] * i2));
    q1[(size_t)row * D + t + 256 * i] = c1.__x;
    q2[(size_t)row * D + t + 256 * i] = c2.__x;
  }
  if (t == 0) diag[row] = dd * i1 * i2;
}

// ---------------- shared 128x128 MX-fp8 MFMA tile (K=128 per instruction) ----------------
// LDS: row*128B, 8 slots of 16B, physical slot = logical ^ (row&7).
// Lane (quad q) needs logical slots 2q,2q+1 = source k [q*32,q*32+32); the
// concat order (lo=logical 2q, hi=2q+1) is compile-time static so both b128s
// land directly in the operand's register pair halves. Scale 127 (E8M0) = x1.0
// -> bit-identical to plain fp8 MFMA (verified R7, absmax 0).
// Register discipline: preload bf[4] (32 regs), STREAM af per i (8 regs) to
// stay under the unified 170-reg/wave cap at 3 waves/EU (R7 spilled here).
__device__ __forceinline__ void mm_tile_fp8(
    const unsigned char* __restrict__ X, const unsigned char* __restrict__ Y,
    int r0, int c0, unsigned char* At, unsigned char* Bt, f32x4 (&acc)[4][4],
    int t, int lr, int quad, int rw, int cw) {
  const f32x4 vzero = {0.0f, 0.0f, 0.0f, 0.0f};
#pragma unroll
  for (int i = 0; i < 4; i++)
#pragma unroll
    for (int j = 0; j < 4; j++) acc[i][j] = vzero;

  for (int kc = 0; kc < 4; kc++) {
    int k0 = kc * BKB;
    __syncthreads(); // LDS reuse guard
#pragma unroll
    for (int it = 0; it < 4; it++) {
      int s = it * 256 + t; // 1024 slots of 16B
      int row = s >> 3, cs = s & 7;
      int src = cs ^ (row & 7);
      gload_lds16(X + (size_t)(r0 + row) * D + k0 + src * 16, &At[s * 16]);
    }
#pragma unroll
    for (int it = 0; it < 4; it++) {
      int s = it * 256 + t;
      int row = s >> 3, cs = s & 7;
      int src = cs ^ (row & 7);
      gload_lds16(Y + (size_t)(c0 + row) * D + k0 + src * 16, &Bt[s * 16]);
    }
    __syncthreads(); // drains vmcnt -> tiles ready

    i32x8 bf[4];
#pragma unroll
    for (int j = 0; j < 4; j++) {
      int row = cw * 64 + j * 16 + lr;
      int sw = row & 7;
      i32x4 lo = *(const i32x4*)&Bt[row * BKB + ((2 * quad) ^ sw) * 16];
      i32x4 hi = *(const i32x4*)&Bt[row * BKB + ((2 * quad + 1) ^ sw) * 16];
      bf[j] = __builtin_shufflevector(lo, hi, 0, 1, 2, 3, 4, 5, 6, 7);
    }
#pragma unroll
    for (int i = 0; i < 4; i++) {
      int row = rw * 64 + i * 16 + lr;
      int sw = row & 7;
      i32x4 lo = *(const i32x4*)&At[row * BKB + ((2 * quad) ^ sw) * 16];
      i32x4 hi = *(const i32x4*)&At[row * BKB + ((2 * quad + 1) ^ sw) * 16];
      i32x8 af = __builtin_shufflevector(lo, hi, 0, 1, 2, 3, 4, 5, 6, 7);
#pragma unroll
      for (int j = 0; j < 4; j++)
        acc[i][j] = __builtin_amdgcn_mfma_scale_f32_16x16x128_f8f6f4(
            af, bf[j], acc[i][j], 0, 0, 0, 127, 0, 127);
    }
  }
}

// ---------------- S pass: one 128x128 tile, row + col sums of exp2(scale*g) ----------------
__global__ __launch_bounds__(256, 3) void s_kernel(
    const unsigned char* __restrict__ q1, const unsigned char* __restrict__ q2,
    float* __restrict__ rowS, float* __restrict__ colS) {
  __shared__ unsigned char At[BM * BKB];
  __shared__ unsigned char Bt[BM * BKB];
  __shared__ float redA[2][BM];
  __shared__ float redC[2][BM];

  int bx = blockIdx.x;
  int t = threadIdx.x;
  int lane = t & 63;
  int wave = t >> 6;
  int quad = lane >> 4;
  int lr = lane & 15;
  int rw = wave >> 1;
  int cw = wave & 1;
  const float scale = 1.4426950408889634f / 0.04f; // log2(e)/T

  int strip = bx >> 6;
  int ct = bx & 63;
  int r0 = strip * BM;
  int c0 = ct * BM;

  f32x4 acc[4][4];
  mm_tile_fp8(q1, q2, r0, c0, At, Bt, acc, t, lr, quad, rw, cw);

  float rowacc[4][4];
  float colacc[4] = {0.0f, 0.0f, 0.0f, 0.0f};
#pragma unroll
  for (int i = 0; i < 4; i++)
#pragma unroll
    for (int r = 0; r < 4; r++) rowacc[i][r] = 0.0f;
#pragma unroll
  for (int i = 0; i < 4; i++)
#pragma unroll
    for (int j = 0; j < 4; j++)
#pragma unroll
      for (int r = 0; r < 4; r++) {
        float e = __builtin_amdgcn_exp2f(acc[i][j][r] * scale);
        rowacc[i][r] += e;
        colacc[j] += e;
      }
#pragma unroll
  for (int j = 0; j < 4; j++) {
    colacc[j] += __shfl_xor(colacc[j], 16);
    colacc[j] += __shfl_xor(colacc[j], 32);
  }
  if (lane < 16) {
#pragma unroll
    for (int j = 0; j < 4; j++) redA[rw][cw * 64 + j * 16 + lr] = colacc[j];
  }
  __syncthreads();
  if (t < BM) colS[(size_t)strip * N + c0 + t] = redA[0][t] + redA[1][t];

#pragma unroll
  for (int i = 0; i < 4; i++)
#pragma unroll
    for (int r = 0; r < 4; r++) {
      float v = rowacc[i][r];
#pragma unroll
      for (int off = 1; off < 16; off <<= 1) v += __shfl_xor(v, off);
      if (lr == 0) redC[cw][rw * 64 + i * 16 + quad * 4 + r] = v;
    }
  __syncthreads();
  if (t < BM) rowS[(size_t)ct * N + r0 + t] = redC[0][t] + redC[1][t];
}

// ---------------- G pass: one upper-triangle Gram tile, dual row/col max ----------------
__global__ __launch_bounds__(256, 3) void g_kernel(
    const unsigned char* __restrict__ q1, const unsigned char* __restrict__ q2,
    float* __restrict__ partG) {
  __shared__ unsigned char At[BM * BKB];
  __shared__ unsigned char Bt[BM * BKB];
  __shared__ float redA[2][BM];
  __shared__ float redB[2][BM];

  int bx = blockIdx.x;
  int t = threadIdx.x;
  int lane = t & 63;
  int wave = t >> 6;
  int quad = lane >> 4;
  int lr = lane & 15;
  int rw = wave >> 1;
  int cw = wave & 1;

  int g = (bx >= TRI) ? 1 : 0;
  int tri = bx - g * TRI;
  int a = (int)((sqrtf(8.0f * (float)tri + 1.0f) - 1.0f) * 0.5f);
  while ((a + 1) * (a + 2) / 2 <= tri) a++;
  while (a * (a + 1) / 2 > tri) a--;
  int b = tri - a * (a + 1) / 2; // b <= a
  const unsigned char* X = g ? q2 : q1;
  int r0 = a * BM;
  int c0 = b * BM;
  bool diagb = (a == b);

  f32x4 acc[4][4];
  mm_tile_fp8(X, X, r0, c0, At, Bt, acc, t, lr, quad, rw, cw);

  // row max (rows of strip a), diagonal masked on diagonal tiles
#pragma unroll
  for (int i = 0; i < 4; i++)
#pragma unroll
    for (int r = 0; r < 4; r++) {
      int rr = rw * 64 + i * 16 + quad * 4 + r;
      float v = -3.0e38f;
#pragma unroll
      for (int j = 0; j < 4; j++) {
        float x = acc[i][j][r];
        int cc = cw * 64 + j * 16 + lr;
        if (diagb && cc == rr) x = -3.0e38f;
        v = fmaxf(v, x);
      }
#pragma unroll
      for (int off = 1; off < 16; off <<= 1) v = fmaxf(v, __shfl_xor(v, off));
      if (lr == 0) redA[cw][rr] = v;
    }
  __syncthreads();
  if (t < BM)
    partG[((size_t)(g * NSTRIP + b)) * N + r0 + t] = fmaxf(redA[0][t], redA[1][t]);

  if (!diagb) {
    // col max == row max for rows of strip b (Gram symmetry)
#pragma unroll
    for (int j = 0; j < 4; j++) {
      float m = acc[0][j][0];
#pragma unroll
      for (int i = 0; i < 4; i++)
#pragma unroll
        for (int r = 0; r < 4; r++) m = fmaxf(m, acc[i][j][r]);
      m = fmaxf(m, __shfl_xor(m, 16));
      m = fmaxf(m, __shfl_xor(m, 32));
      if (lane < 16) redB[rw][cw * 64 + j * 16 + lr] = m;
    }
    __syncthreads();
    if (t < BM)
      partG[((size_t)(g * NSTRIP + a)) * N + c0 + t] = fmaxf(redB[0][t], redB[1][t]);
  }
}

// ---------------- per-row combine of partials ----------------
__global__ __launch_bounds__(256) void combine_kernel(
    const float* __restrict__ diag,
    const float* __restrict__ rowS, const float* __restrict__ colS,
    const float* __restrict__ partG, float* __restrict__ bp) {
  const float invT = 25.0f;
  int i = blockIdx.x * 256 + threadIdx.x;

  float s = 0.0f;
  for (int q = 0; q < NSTRIP; q++) s += rowS[(size_t)q * N + i];
  float a12 = logf(s) - diag[i] * invT;

  s = 0.0f;
  for (int o = 0; o < NSTRIP; o++) s += colS[(size_t)o * N + i];
  float a21 = logf(s) - diag[i] * invT;

  float g1 = -3.0e38f, g2 = -3.0e38f;
  for (int o = 0; o < NSTRIP; o++) {
    g1 = fmaxf(g1, partG[(size_t)o * N + i]);
    g2 = fmaxf(g2, partG[(size_t)(NSTRIP + o) * N + i]);
  }
  float k1 = logf(sqrtf(fmaxf(2.0f - 2.0f * g1, 0.0f)) + 1e-9f);
  float k2 = logf(sqrtf(fmaxf(2.0f - 2.0f * g2, 0.0f)) + 1e-9f);

#pragma unroll
  for (int off = 1; off < 64; off <<= 1) {
    a12 += __shfl_xor(a12, off);
    a21 += __shfl_xor(a21, off);
    k1  += __shfl_xor(k1,  off);
    k2  += __shfl_xor(k2,  off);
  }
  __shared__ float fr[4][4];
  int wv = threadIdx.x >> 6;
  if ((threadIdx.x & 63) == 0) { fr[0][wv] = a12; fr[1][wv] = a21; fr[2][wv] = k1; fr[3][wv] = k2; }
  __syncthreads();
  if (threadIdx.x == 0) {
    bp[blockIdx.x * 4 + 0] = fr[0][0] + fr[0][1] + fr[0][2] + fr[0][3];
    bp[blockIdx.x * 4 + 1] = fr[1][0] + fr[1][1] + fr[1][2] + fr[1][3];
    bp[blockIdx.x * 4 + 2] = fr[2][0] + fr[2][1] + fr[2][2] + fr[2][3];
    bp[blockIdx.x * 4 + 3] = fr[3][0] + fr[3][1] + fr[3][2] + fr[3][3];
  }
}

__global__ __launch_bounds__(64) void final_kernel(const float* __restrict__ bp,
                                                   float* __restrict__ out) {
  int t = threadIdx.x;
  float a12 = 0.f, a21 = 0.f, k1 = 0.f, k2 = 0.f;
  if (t < 32) {
    a12 = bp[t * 4 + 0];
    a21 = bp[t * 4 + 1];
    k1  = bp[t * 4 + 2];
    k2  = bp[t * 4 + 3];
  }
#pragma unroll
  for (int off = 1; off < 64; off <<= 1) {
    a12 += __shfl_xor(a12, off);
    a21 += __shfl_xor(a21, off);
    k1  += __shfl_xor(k1,  off);
    k2  += __shfl_xor(k2,  off);
  }
  if (t == 0) {
    float contrastive = 0.5f * (a12 + a21) / (float)N;
    float koleo = -0.5f * (k1 + k2) / (float)N;
    out[0] = contrastive + 0.1f * koleo;
  }
}

extern "C" void kernel_launch(void* const* d_in, const int* in_sizes, int n_in,
                              void* d_out, int out_size, void* d_ws, size_t ws_size,
                              hipStream_t stream) {
  const float* z1 = (const float*)d_in[0];
  const float* z2 = (const float*)d_in[1];
  char* w = (char*)d_ws;
  unsigned char* q1 = (unsigned char*)w; w += (size_t)N * D;
  unsigned char* q2 = (unsigned char*)w; w += (size_t)N * D;
  float* diag = (float*)w;   w += (size_t)N * sizeof(float);
  float* rowS = (float*)w;   w += (size_t)NSTRIP * N * sizeof(float);
  float* colS = (float*)w;   w += (size_t)NSTRIP * N * sizeof(float);
  float* partG = (float*)w;  w += (size_t)2 * NSTRIP * N * sizeof(float);
  float* bp = (float*)w;     w += (size_t)32 * 4 * sizeof(float);
  float* out = (float*)d_out;

  norm_kernel<<<N, 256, 0, stream>>>(z1, z2, q1, q2, diag);
  s_kernel<<<S_BLOCKS, 256, 0, stream>>>(q1, q2, rowS, colS);
  g_kernel<<<G_BLOCKS, 256, 0, stream>>>(q1, q2, partG);
  combine_kernel<<<N / 256, 256, 0, stream>>>(diag, rowS, colS, partG, bp);
  final_kernel<<<1, 64, 0, stream>>>(bp, out);
}

// Round 9
// 190.739 us; speedup vs baseline: 2.1357x; 2.1357x over previous
//
#include <hip/hip_runtime.h>
#include <hip/hip_bf16.h>
#include <hip/hip_fp8.h>
#include <math.h>

#define N 8192
#define D 512
#define BM 128
#define BK 64
#define NSTRIP 64                       // N / BM
#define S_BLOCKS (NSTRIP * NSTRIP)      // 4096 S tiles
#define TRI (NSTRIP * (NSTRIP + 1) / 2) // 2080
#define G_BLOCKS (2 * TRI)              // 4160 Gram tiles
#define SG_BLOCKS (S_BLOCKS + G_BLOCKS) // 8256

typedef float f32x4 __attribute__((ext_vector_type(4)));
typedef long l2 __attribute__((ext_vector_type(2)));

__device__ inline void gload_lds16(const void* g, void* l) {
  __builtin_amdgcn_global_load_lds(
      (const __attribute__((address_space(1))) void*)g,
      (__attribute__((address_space(3))) void*)l, 16, 0, 0);
}

// ---------------- normalize to fp8 e4m3 + exact fp32 diagonal + zero out ----------------
__global__ __launch_bounds__(256) void norm_kernel(
    const float* __restrict__ z1, const float* __restrict__ z2,
    unsigned char* __restrict__ q1, unsigned char* __restrict__ q2,
    float* __restrict__ diag, float* __restrict__ out) {
  int row = blockIdx.x;
  int t = threadIdx.x;
  if (row == 0 && t == 0) out[0] = 0.0f; // atomic target for combine (stream-ordered)
  const float* a = z1 + (size_t)row * D;
  const float* b = z2 + (size_t)row * D;
  float va[2], vb[2];
  float ss1 = 0.f, ss2 = 0.f, dd = 0.f;
#pragma unroll
  for (int i = 0; i < 2; i++) {
    float x = a[t + 256 * i];
    float y = b[t + 256 * i];
    va[i] = x; vb[i] = y;
    ss1 += x * x; ss2 += y * y; dd += x * y;
  }
#pragma unroll
  for (int off = 1; off < 64; off <<= 1) {
    ss1 += __shfl_xor(ss1, off);
    ss2 += __shfl_xor(ss2, off);
    dd  += __shfl_xor(dd,  off);
  }
  __shared__ float red[3][4];
  int wv = t >> 6;
  if ((t & 63) == 0) { red[0][wv] = ss1; red[1][wv] = ss2; red[2][wv] = dd; }
  __syncthreads();
  ss1 = red[0][0] + red[0][1] + red[0][2] + red[0][3];
  ss2 = red[1][0] + red[1][1] + red[1][2] + red[1][3];
  dd  = red[2][0] + red[2][1] + red[2][2] + red[2][3];
  float i1 = 1.0f / fmaxf(sqrtf(ss1), 1e-12f);
  float i2 = 1.0f / fmaxf(sqrtf(ss2), 1e-12f);
#pragma unroll
  for (int i = 0; i < 2; i++) {
    __hip_fp8_e4m3 c1((float)(va[i] * i1)); // OCP e4m3fn
    __hip_fp8_e4m3 c2((float)(vb[i] * i2));
    q1[(size_t)row * D + t + 256 * i] = c1.__x;
    q2[(size_t)row * D + t + 256 * i] = c2.__x;
  }
  if (t == 0) diag[row] = dd * i1 * i2;
}

// ---------------- shared 128x128 fp8 MFMA tile (R6-proven, 64 VGPR) ----------------
// LDS layout per tile: row*64 + slot*16, physical slot = cs ^ ((row>>1)&3).
// A lane's b128 at logical quad q covers source k = q*16..q*16+15: low 8B feeds
// ks=0, high 8B ks=1 (k-block relabeling, identical for A and B -> dot correct).
__device__ __forceinline__ void mm_tile_fp8(
    const unsigned char* __restrict__ X, const unsigned char* __restrict__ Y,
    int r0, int c0, unsigned char* At, unsigned char* Bt, f32x4 (&acc)[4][4],
    int t, int lr, int quad, int rw, int cw) {
  const f32x4 vzero = {0.0f, 0.0f, 0.0f, 0.0f};
#pragma unroll
  for (int i = 0; i < 4; i++)
#pragma unroll
    for (int j = 0; j < 4; j++) acc[i][j] = vzero;

  for (int kc = 0; kc < 8; kc++) {
    int k0 = kc * BK;
    __syncthreads(); // LDS reuse guard
#pragma unroll
    for (int it = 0; it < 2; it++) {
      int s = it * 256 + t; // 512 slots of 16B
      int row = s >> 2, cs = s & 3;
      int src = cs ^ ((row >> 1) & 3); // conflict-spread swizzle
      gload_lds16(X + (size_t)(r0 + row) * D + k0 + src * 16, &At[s * 16]);
    }
#pragma unroll
    for (int it = 0; it < 2; it++) {
      int s = it * 256 + t;
      int row = s >> 2, cs = s & 3;
      int src = cs ^ ((row >> 1) & 3);
      gload_lds16(Y + (size_t)(c0 + row) * D + k0 + src * 16, &Bt[s * 16]);
    }
    __syncthreads(); // drains vmcnt -> tiles ready

    l2 af[4], bf[4];
#pragma unroll
    for (int i = 0; i < 4; i++) {
      int row = rw * 64 + i * 16 + lr;
      int ps = quad ^ ((row >> 1) & 3);
      af[i] = *(const l2*)&At[row * 64 + ps * 16];
    }
#pragma unroll
    for (int j = 0; j < 4; j++) {
      int row = cw * 64 + j * 16 + lr;
      int ps = quad ^ ((row >> 1) & 3);
      bf[j] = *(const l2*)&Bt[row * 64 + ps * 16];
    }
#pragma unroll
    for (int i = 0; i < 4; i++)
#pragma unroll
      for (int j = 0; j < 4; j++)
        acc[i][j] = __builtin_amdgcn_mfma_f32_16x16x32_fp8_fp8(af[i].x, bf[j].x, acc[i][j], 0, 0, 0);
#pragma unroll
    for (int i = 0; i < 4; i++)
#pragma unroll
      for (int j = 0; j < 4; j++)
        acc[i][j] = __builtin_amdgcn_mfma_f32_16x16x32_fp8_fp8(af[i].y, bf[j].y, acc[i][j], 0, 0, 0);
  }
}

// ---------------- fused S + G pass: one 128x128 tile per block ----------------
// bx < S_BLOCKS: S tile (row/col exp-sums). Else: upper-triangle Gram tile
// (dual row/col max). Both paths share one mm_tile_fp8 instantiation and
// 64-VGPR-parity epilogues (R6-measured).
__global__ __launch_bounds__(256, 3) void sg_kernel(
    const unsigned char* __restrict__ q1, const unsigned char* __restrict__ q2,
    float* __restrict__ rowS, float* __restrict__ colS,
    float* __restrict__ partG) {
  __shared__ unsigned char At[BM * BK];
  __shared__ unsigned char Bt[BM * BK];
  __shared__ float redA[2][BM];
  __shared__ float redB[2][BM];

  int bx = blockIdx.x;
  int t = threadIdx.x;
  int lane = t & 63;
  int wave = t >> 6;
  int quad = lane >> 4;
  int lr = lane & 15;
  int rw = wave >> 1;
  int cw = wave & 1;
  const float scale = 1.4426950408889634f / 0.04f; // log2(e)/T

  bool smode = bx < S_BLOCKS;
  const unsigned char* X;
  const unsigned char* Y;
  int r0, c0, ga = 0, gb = 0, gg = 0;
  bool diagb = false;
  if (smode) {
    r0 = (bx >> 6) * BM;
    c0 = (bx & 63) * BM;
    X = q1; Y = q2;
  } else {
    int gx = bx - S_BLOCKS;
    gg = (gx >= TRI) ? 1 : 0;
    int tri = gx - gg * TRI;
    int a = (int)((sqrtf(8.0f * (float)tri + 1.0f) - 1.0f) * 0.5f);
    while ((a + 1) * (a + 2) / 2 <= tri) a++;
    while (a * (a + 1) / 2 > tri) a--;
    int b = tri - a * (a + 1) / 2; // b <= a
    ga = a; gb = b;
    X = gg ? q2 : q1; Y = X;
    r0 = a * BM;
    c0 = b * BM;
    diagb = (a == b);
  }

  f32x4 acc[4][4];
  mm_tile_fp8(X, Y, r0, c0, At, Bt, acc, t, lr, quad, rw, cw);

  if (smode) {
    // ---- row + col sums of exp2(scale*g); fixed reference (fits fp32) ----
    float rowacc[4][4];
    float colacc[4] = {0.0f, 0.0f, 0.0f, 0.0f};
#pragma unroll
    for (int i = 0; i < 4; i++)
#pragma unroll
      for (int r = 0; r < 4; r++) rowacc[i][r] = 0.0f;
#pragma unroll
    for (int i = 0; i < 4; i++)
#pragma unroll
      for (int j = 0; j < 4; j++)
#pragma unroll
        for (int r = 0; r < 4; r++) {
          float e = __builtin_amdgcn_exp2f(acc[i][j][r] * scale);
          rowacc[i][r] += e;
          colacc[j] += e;
        }
#pragma unroll
    for (int j = 0; j < 4; j++) {
      colacc[j] += __shfl_xor(colacc[j], 16);
      colacc[j] += __shfl_xor(colacc[j], 32);
    }
    if (lane < 16) {
#pragma unroll
      for (int j = 0; j < 4; j++) redA[rw][cw * 64 + j * 16 + lr] = colacc[j];
    }
    __syncthreads();
    if (t < BM) colS[(size_t)(r0 >> 7) * N + c0 + t] = redA[0][t] + redA[1][t];

#pragma unroll
    for (int i = 0; i < 4; i++)
#pragma unroll
      for (int r = 0; r < 4; r++) {
        float v = rowacc[i][r];
#pragma unroll
        for (int off = 1; off < 16; off <<= 1) v += __shfl_xor(v, off);
        if (lr == 0) redB[cw][rw * 64 + i * 16 + quad * 4 + r] = v;
      }
    __syncthreads();
    if (t < BM) rowS[(size_t)(c0 >> 7) * N + r0 + t] = redB[0][t] + redB[1][t];
  } else {
    // ---- Gram: row max (strip a), diag-masked; col max = row max of strip b ----
#pragma unroll
    for (int i = 0; i < 4; i++)
#pragma unroll
      for (int r = 0; r < 4; r++) {
        int rr = rw * 64 + i * 16 + quad * 4 + r;
        float v = -3.0e38f;
#pragma unroll
        for (int j = 0; j < 4; j++) {
          float x = acc[i][j][r];
          int cc = cw * 64 + j * 16 + lr;
          if (diagb && cc == rr) x = -3.0e38f;
          v = fmaxf(v, x);
        }
#pragma unroll
        for (int off = 1; off < 16; off <<= 1) v = fmaxf(v, __shfl_xor(v, off));
        if (lr == 0) redA[cw][rr] = v;
      }
    __syncthreads();
    if (t < BM)
      partG[((size_t)(gg * NSTRIP + gb)) * N + r0 + t] = fmaxf(redA[0][t], redA[1][t]);

    if (!diagb) {
#pragma unroll
      for (int j = 0; j < 4; j++) {
        float m = acc[0][j][0];
#pragma unroll
        for (int i = 0; i < 4; i++)
#pragma unroll
          for (int r = 0; r < 4; r++) m = fmaxf(m, acc[i][j][r]);
        m = fmaxf(m, __shfl_xor(m, 16));
        m = fmaxf(m, __shfl_xor(m, 32));
        if (lane < 16) redB[rw][cw * 64 + j * 16 + lr] = m;
      }
      __syncthreads();
      if (t < BM)
        partG[((size_t)(gg * NSTRIP + ga)) * N + c0 + t] = fmaxf(redB[0][t], redB[1][t]);
    }
  }
}

// ---------------- per-row combine of partials -> atomic scalar ----------------
__global__ __launch_bounds__(256) void combine_kernel(
    const float* __restrict__ diag,
    const float* __restrict__ rowS, const float* __restrict__ colS,
    const float* __restrict__ partG, float* __restrict__ out) {
  const float invT = 25.0f;
  int i = blockIdx.x * 256 + threadIdx.x;

  float s = 0.0f;
  for (int q = 0; q < NSTRIP; q++) s += rowS[(size_t)q * N + i];
  float a12 = logf(s) - diag[i] * invT;

  s = 0.0f;
  for (int o = 0; o < NSTRIP; o++) s += colS[(size_t)o * N + i];
  float a21 = logf(s) - diag[i] * invT;

  float g1 = -3.0e38f, g2 = -3.0e38f;
  for (int o = 0; o < NSTRIP; o++) {
    g1 = fmaxf(g1, partG[(size_t)o * N + i]);
    g2 = fmaxf(g2, partG[(size_t)(NSTRIP + o) * N + i]);
  }
  float k1 = logf(sqrtf(fmaxf(2.0f - 2.0f * g1, 0.0f)) + 1e-9f);
  float k2 = logf(sqrtf(fmaxf(2.0f - 2.0f * g2, 0.0f)) + 1e-9f);

  // per-thread contribution to the final scalar
  float c = 0.5f * (a12 + a21) / (float)N - 0.1f * 0.5f * (k1 + k2) / (float)N;
#pragma unroll
  for (int off = 1; off < 64; off <<= 1) c += __shfl_xor(c, off);
  __shared__ float fr[4];
  int wv = threadIdx.x >> 6;
  if ((threadIdx.x & 63) == 0) fr[wv] = c;
  __syncthreads();
  if (threadIdx.x == 0)
    atomicAdd(out, fr[0] + fr[1] + fr[2] + fr[3]); // device-scope, out zeroed by norm_kernel
}

extern "C" void kernel_launch(void* const* d_in, const int* in_sizes, int n_in,
                              void* d_out, int out_size, void* d_ws, size_t ws_size,
                              hipStream_t stream) {
  const float* z1 = (const float*)d_in[0];
  const float* z2 = (const float*)d_in[1];
  char* w = (char*)d_ws;
  unsigned char* q1 = (unsigned char*)w; w += (size_t)N * D;
  unsigned char* q2 = (unsigned char*)w; w += (size_t)N * D;
  float* diag = (float*)w;   w += (size_t)N * sizeof(float);
  float* rowS = (float*)w;   w += (size_t)NSTRIP * N * sizeof(float);
  float* colS = (float*)w;   w += (size_t)NSTRIP * N * sizeof(float);
  float* partG = (float*)w;  w += (size_t)2 * NSTRIP * N * sizeof(float);
  float* out = (float*)d_out;

  norm_kernel<<<N, 256, 0, stream>>>(z1, z2, q1, q2, diag, out);
  sg_kernel<<<SG_BLOCKS, 256, 0, stream>>>(q1, q2, rowS, colS, partG);
  combine_kernel<<<N / 256, 256, 0, stream>>>(diag, rowS, colS, partG, out);
}